// Round 11
// baseline (1085.730 us; speedup 1.0000x reference)
//
#include <hip/hip_runtime.h>
#include <stdint.h>

#define NBLK 256
#define TPB  512

typedef float f32x4 __attribute__((ext_vector_type(4)));
typedef float f32x2 __attribute__((ext_vector_type(2)));

// ---------------- threefry2x32 (exact JAX partitionable semantics) -------
__device__ __forceinline__ uint32_t rotl32(uint32_t x, int r) {
  return (x << r) | (x >> (32 - r));
}

__device__ __forceinline__ void tf2x32(uint32_t k0, uint32_t k1,
                                       uint32_t x0, uint32_t x1,
                                       uint32_t& o0, uint32_t& o1) {
  const uint32_t k2 = k0 ^ k1 ^ 0x1BD11BDAu;
#define TFR(r) x0 += x1; x1 = rotl32(x1, (r)); x1 ^= x0;
  x0 += k0; x1 += k1;
  TFR(13) TFR(15) TFR(26) TFR(6)
  x0 += k1; x1 += k2 + 1u;
  TFR(17) TFR(29) TFR(16) TFR(24)
  x0 += k2; x1 += k0 + 2u;
  TFR(13) TFR(15) TFR(26) TFR(6)
  x0 += k0; x1 += k1 + 3u;
  TFR(17) TFR(29) TFR(16) TFR(24)
  x0 += k1; x1 += k2 + 4u;
  TFR(13) TFR(15) TFR(26) TFR(6)
  x0 += k2; x1 += k0 + 5u;
#undef TFR
  o0 = x0; o1 = x1;
}

__device__ __forceinline__ float bits_to_u01(uint32_t b) {
  return __uint_as_float((b >> 9) | 0x3f800000u) - 1.0f;
}

__device__ __forceinline__ float gumbel_from_bits(uint32_t b) {
  float u = bits_to_u01(b);
  u = (u == 0.0f) ? 1.17549435e-38f : u;
  return -logf(-logf(u));
}

__device__ __forceinline__ float sigf(float x) { return 1.0f / (1.0f + expf(-x)); }

// coherent (cross-XCD) accesses: sc0 sc1 -> device coherence point.
__device__ __forceinline__ f32x4 ldg_cohx4(const float* p) {
  f32x4 v;
  asm volatile("global_load_dwordx4 %0, %1, off sc0 sc1\n\ts_waitcnt vmcnt(0)"
               : "=v"(v) : "v"(p) : "memory");
  return v;
}
__device__ __forceinline__ void stg_cohx4(float* p, f32x4 v) {
  asm volatile("global_store_dwordx4 %0, %1, off sc0 sc1"
               :: "v"(p), "v"(v) : "memory");
}
__device__ __forceinline__ void stg_cohx2(float* p, f32x2 v) {
  asm volatile("global_store_dwordx2 %0, %1, off sc0 sc1"
               :: "v"(p), "v"(v) : "memory");
}

// Two-deep pipelined dual-chunk poll: one probe pair always in flight, so
// detection delay after data lands ~= one load latency (not two).
__device__ __forceinline__ void poll2(const float* s1, const float* s2,
                                      float tagf, f32x4& r1, f32x4& r2) {
  f32x4 a, b;
  asm volatile("global_load_dwordx4 %0, %2, off sc0 sc1\n\t"
               "global_load_dwordx4 %1, %3, off sc0 sc1"
               : "=&v"(a), "=&v"(b) : "v"(s1), "v"(s2) : "memory");
  for (;;) {
    f32x4 c, d;
    asm volatile("global_load_dwordx4 %0, %2, off sc0 sc1\n\t"
                 "global_load_dwordx4 %1, %3, off sc0 sc1\n\t"
                 "s_waitcnt vmcnt(2)"
                 : "=&v"(c), "=&v"(d) : "v"(s1), "v"(s2) : "memory");
    if (a.y == tagf && a.w == tagf && b.y == tagf && b.w == tagf) {
      asm volatile("s_waitcnt vmcnt(0)" ::: "memory");
      r1 = a; r2 = b; return;
    }
    asm volatile("s_waitcnt vmcnt(0)" ::: "memory");
    if (c.y == tagf && c.w == tagf && d.y == tagf && d.w == tagf) {
      r1 = c; r2 = d; return;
    }
    asm volatile("global_load_dwordx4 %0, %2, off sc0 sc1\n\t"
                 "global_load_dwordx4 %1, %3, off sc0 sc1"
                 : "=&v"(a), "=&v"(b) : "v"(s1), "v"(s2) : "memory");
  }
}
// Two-deep pipelined single-chunk poll.
__device__ __forceinline__ f32x4 poll1(const float* s, float tagf) {
  f32x4 a;
  asm volatile("global_load_dwordx4 %0, %1, off sc0 sc1"
               : "=&v"(a) : "v"(s) : "memory");
  for (;;) {
    f32x4 c;
    asm volatile("global_load_dwordx4 %0, %1, off sc0 sc1\n\t"
                 "s_waitcnt vmcnt(1)"
                 : "=&v"(c) : "v"(s) : "memory");
    if (a.y == tagf && a.w == tagf) {
      asm volatile("s_waitcnt vmcnt(0)" ::: "memory");
      return a;
    }
    asm volatile("s_waitcnt vmcnt(0)" ::: "memory");
    if (c.y == tagf && c.w == tagf) return c;
    asm volatile("global_load_dwordx4 %0, %1, off sc0 sc1"
                 : "=&v"(a) : "v"(s) : "memory");
  }
}

// ---------------- sampling for step s (redundant in every wave) ----------
__device__ __forceinline__ void do_sample(
    int s, int l, const float* __restrict__ zl,
    const float (*gum)[16], const float (*uni)[64],
    bool wr, float* __restrict__ dout,
    float& x_l, float& x2_l) {
  const int j = l & 7;
  float bv; int bi;
  {
    const float a_lo = gum[s][j]     + 2.5f * tanhf(zl[j] / 5.0f);
    const float a_hi = gum[s][j + 8] + 2.5f * tanhf(zl[j + 8] / 5.0f);
    if (a_hi > a_lo) { bv = a_hi; bi = j + 8; } else { bv = a_lo; bi = j; }
  }
#pragma unroll
  for (int d = 1; d < 8; d <<= 1) {
    const float ov = __shfl_xor(bv, d, 64);
    const int   oi = __shfl_xor(bi, d, 64);
    if (ov > bv || (ov == bv && oi < bi)) { bv = ov; bi = oi; }
  }
  const int idx1 = bi;

  const int j32 = l & 31;
  const int ci = s >> 1;
  const float cc = (float)ci;
  const float sa = -log1pf(cc * expf(-zl[16 + j32]));
  const float sb = -log1pf(cc * expf(-zl[48 + j32]));
  const float pa = expf(sa);
  const float pb = expf(sb);
  const float blo = ((uni[s][j32] < pa) && (j32 < ci)) ? 1.0f : 0.0f;
  const float bhi = ((uni[s][j32 + 32] < pb) && (j32 + 32 < ci)) ? 1.0f : 0.0f;

  const float v1 = __shfl(blo, (l - 16) & 63, 64);
  const float v2 = __shfl(bhi, (l - 48) & 63, 64);
  const float v3 = __shfl(bhi, (l + 16) & 63, 64);
  x_l  = (l < 16) ? ((idx1 == l) ? 1.0f : 0.0f) : ((l < 48) ? v1 : v2);
  x2_l = (l < 16) ? v3 : 0.0f;

  if (wr) {
    const float lgt = 2.5f * tanhf(zl[l & 15] / 5.0f);
    float mx = lgt;
#pragma unroll
    for (int d = 1; d < 16; d <<= 1) mx = fmaxf(mx, __shfl_xor(mx, d, 64));
    float sm = expf(lgt - mx);
#pragma unroll
    for (int d = 1; d < 16; d <<= 1) sm += __shfl_xor(sm, d, 64);
    const float ls = lgt - mx - logf(sm);
    if (l < 16) {
      dout[s * 16 + l] = ls;
      dout[10240 + s * 16 + l] = (idx1 == l) ? 1.0f : 0.0f;
    }
    if (l < 32) {
      dout[2048 + s * 64 + l]       = sa;
      dout[2048 + s * 64 + 32 + l]  = sb;
      dout[12288 + s * 64 + l]      = blo;
      dout[12288 + s * 64 + 32 + l] = bhi;
    }
  }
}

__device__ __forceinline__ int perm(int e) {
  return (((e >> 2) & 7) << 8) | ((e >> 5) << 2) | (e & 3);
}

// ---------------- persistent controller kernel ----------------
// 256 blocks x 512 threads, 1 block/CU (launch_bounds(512,1) -> 2 waves/
// SIMD -> 256-reg budget; R10 confirmed no spill at this geometry).
__global__ void __launch_bounds__(TPB, 1)
ctrl_kernel(const float* __restrict__ W_ih, const float* __restrict__ W_hh,
            const float* __restrict__ b_ih, const float* __restrict__ b_hh,
            const float* __restrict__ fc1w, const float* __restrict__ fc1b,
            const float* __restrict__ fc2w, const float* __restrict__ fc2b,
            float* __restrict__ dout, void* __restrict__ ws) {
  const int bid = blockIdx.x;
  const int tid = threadIdx.x;
  const int wv = tid >> 6;    // wave 0..7
  const int l  = tid & 63;

  // ws: htag[2][4096] dwords (2048 elems x (v,t)) ; ztag[2][160] dwords
  float* htag = (float*)ws;
  float* ztag = htag + 8192;

  __shared__ float gum[128][16];
  __shared__ float uni[128][64];
  __shared__ __align__(16) float h_lds[2048];
  __shared__ float z_lds[80];
  __shared__ float gbuf[8][4];
  __shared__ double zpd[8];
  __shared__ float c_lds[8];

  // --- RNG tables (partitionable threefry; verified R3) ---
  if (tid < 8) c_lds[tid] = 0.0f;
  {
    const int s = tid >> 2;   // step
    const int c = tid & 3;    // chunk
    uint32_t ka, kb, c0, c1, d0, d1;
    tf2x32(0u, 42u, 0u, (uint32_t)s, ka, kb);
    tf2x32(ka, kb, 0u, 0u, c0, c1);
    tf2x32(ka, kb, 0u, 1u, d0, d1);
#pragma unroll
    for (int q = 0; q < 4; ++q) {
      const int j = 4 * c + q;
      uint32_t lo, hi;
      tf2x32(c0, c1, 0u, (uint32_t)j, lo, hi);
      gum[s][j] = gumbel_from_bits(lo ^ hi);
    }
#pragma unroll
    for (int q = 0; q < 16; ++q) {
      const int j = 16 * c + q;
      uint32_t lo, hi;
      tf2x32(d0, d1, 0u, (uint32_t)j, lo, hi);
      uni[s][j] = bits_to_u01(lo ^ hi);
    }
  }

  // --- register-resident W_hh slice: 4 rows x 32 cols per lane ---
  const int g   = wv >> 1;          // gate 0..3
  const int kb4 = (wv & 1) << 2;    // elem base 0 or 4
  f32x4 Wr[4][8];
  float wih_a[4], wih_b[4], bsum[4];
#pragma unroll
  for (int rr = 0; rr < 4; ++rr) {
    const int r = g * 2048 + bid * 8 + kb4 + rr;
    const float* wp = W_hh + (size_t)r * 2048 + 32 * l;
#pragma unroll
    for (int m = 0; m < 8; ++m)
      Wr[rr][m] = *reinterpret_cast<const f32x4*>(wp + 4 * m);
    wih_a[rr] = W_ih[r * 80 + l];
    wih_b[rr] = (l < 16) ? W_ih[r * 80 + 64 + l] : 0.0f;
    bsum[rr] = b_ih[r] + b_hh[r];
  }
  // PIN: with the 256-reg budget these stay resident (R10: no spill)
#pragma unroll
  for (int rr = 0; rr < 4; ++rr) {
#pragma unroll
    for (int m = 0; m < 8; ++m)
      asm volatile("" : "+v"(Wr[rr][m]));
  }

  f32x2 fcA = (f32x2){0.f, 0.f}, fcB = (f32x2){0.f, 0.f};
  float fcb = 0.0f;
  if (bid < 80) {
    const float* fp = (bid < 16) ? (fc1w + (size_t)bid * 2048)
                                 : (fc2w + (size_t)(bid - 16) * 2048);
    fcA = *reinterpret_cast<const f32x2*>(fp + 2 * tid);          // cols 2t,2t+1
    fcB = *reinterpret_cast<const f32x2*>(fp + 1024 + 2 * tid);   // +1024
    fcb = (bid < 16) ? fc1b[bid] : fc2b[bid - 16];
  }
  __syncthreads();

  float x_l = 0.0f, x2_l = 0.0f;
  const int p0 = perm(2 * tid), p1 = perm(2 * tid + 1);
  const int p2 = perm(1024 + 2 * tid), p3 = perm(1024 + 2 * tid + 1);

#pragma unroll 1
  for (int i = 0; i < 128; ++i) {
    // A: acquire h_i (two 16B (v,t,v,t) chunks, pipelined); stage to LDS.
    f32x4 hv1 = (f32x4){0.f, 0.f, 0.f, 0.f};
    f32x4 hv2 = (f32x4){0.f, 0.f, 0.f, 0.f};
    if (i > 0) {
      const float tagf = (float)i;
      const float* s1 = htag + ((i & 1) << 12) + (tid << 2);
      poll2(s1, s1 + 2048, tagf, hv1, hv2);
    }
    h_lds[p0] = hv1.x;
    h_lds[p1] = hv1.z;
    h_lds[p2] = hv2.x;
    h_lds[p3] = hv2.z;

    // B: heads start z_{i-1} = fc_row . relu(h_i) from the polled regs.
    if (i > 0 && bid < 80) {
      double dp = fma((double)fcA.x, (double)fmaxf(hv1.x, 0.0f),
                      (double)fcA.y * (double)fmaxf(hv1.z, 0.0f));
      dp = fma((double)fcB.x, (double)fmaxf(hv2.x, 0.0f), dp);
      dp = fma((double)fcB.y, (double)fmaxf(hv2.z, 0.0f), dp);
#pragma unroll
      for (int d = 1; d < 64; d <<= 1) dp += __shfl_xor(dp, d, 64);
      if (l == 0) zpd[wv] = dp;
    }
    __syncthreads();  // h_lds + zpd visible
    if (i > 0 && bid < 80 && tid < 8) {
      double v = zpd[tid];
#pragma unroll
      for (int d = 1; d < 8; d <<= 1) v += __shfl_xor(v, d, 64);
      if (tid == 0) {
        const float z = (float)(v + (double)fcb);
        f32x2 zv = (f32x2){z, (float)i};   // tag = i
        stg_cohx2(ztag + (((i - 1) & 1) * 160) + (bid << 1), zv);
      }
    }

    // C: W_hh @ h_i partial from registers (overlaps the z round-trip)
    float acc[4] = {0.f, 0.f, 0.f, 0.f};
#pragma unroll
    for (int m = 0; m < 8; ++m) {
      const f32x4 H = *reinterpret_cast<const f32x4*>(h_lds + (m << 8) + (l << 2));
#pragma unroll
      for (int rr = 0; rr < 4; ++rr) {
        acc[rr] = fmaf(Wr[rr][m].x, H.x, acc[rr]);
        acc[rr] = fmaf(Wr[rr][m].y, H.y, acc[rr]);
        acc[rr] = fmaf(Wr[rr][m].z, H.z, acc[rr]);
        acc[rr] = fmaf(Wr[rr][m].w, H.w, acc[rr]);
      }
    }

    // D: poll z_{i-1} (pipelined), stage, sample x_i
    if (i > 0) {
      const int s = i - 1;
      if (tid < 40) {
        const f32x4 zv = poll1(ztag + ((s & 1) * 160) + (tid << 2), (float)i);
        z_lds[2 * tid]     = zv.x;
        z_lds[2 * tid + 1] = zv.z;
      }
      __syncthreads();
      do_sample(s, l, z_lds, gum, uni, (bid == 0 && wv == 0), dout, x_l, x2_l);
    }

    // E: fold W_ih@x, butterfly-reduce, LSTM cell, publish h_{i+1}
#pragma unroll
    for (int rr = 0; rr < 4; ++rr)
      acc[rr] = fmaf(wih_a[rr], x_l, fmaf(wih_b[rr], x2_l, acc[rr]));
#pragma unroll
    for (int rr = 0; rr < 4; ++rr) {
#pragma unroll
      for (int d = 1; d < 64; d <<= 1)
        acc[rr] += __shfl_xor(acc[rr], d, 64);
    }
    if (l == 0) {
#pragma unroll
      for (int rr = 0; rr < 4; ++rr)
        gbuf[wv][rr] = acc[rr] + bsum[rr];
    }
    __syncthreads();
    if (tid < 8) {
      __builtin_amdgcn_s_setprio(1);
      const int t = tid;
      const float gI = gbuf[0 + (t >> 2)][t & 3];
      const float gF = gbuf[2 + (t >> 2)][t & 3];
      const float gG = gbuf[4 + (t >> 2)][t & 3];
      const float gO = gbuf[6 + (t >> 2)][t & 3];
      const float cn = sigf(gF) * c_lds[t] + sigf(gI) * tanhf(gG);
      const float hn = sigf(gO) * tanhf(cn);
      c_lds[t] = cn;
      const float hnn = __shfl(hn, t + 1, 64);
      if ((t & 1) == 0) {
        const float tagf = (float)(i + 1);
        f32x4 out4 = (f32x4){hn, tagf, hnn, tagf};
        stg_cohx4(htag + (((i + 1) & 1) << 12) + (((bid << 3) + t) << 1), out4);
      }
      __builtin_amdgcn_s_setprio(0);
    }
  }

  // ---- epilogue: z_127 (from h_128) and outputs for step 127 ----
  if (bid >= 80) return;
  {
    const float tagf = 128.0f;
    const float* s1 = htag + (tid << 2);   // buffer 0 holds h_128
    f32x4 hv1, hv2;
    poll2(s1, s1 + 2048, tagf, hv1, hv2);
    double dp = fma((double)fcA.x, (double)fmaxf(hv1.x, 0.0f),
                    (double)fcA.y * (double)fmaxf(hv1.z, 0.0f));
    dp = fma((double)fcB.x, (double)fmaxf(hv2.x, 0.0f), dp);
    dp = fma((double)fcB.y, (double)fmaxf(hv2.z, 0.0f), dp);
#pragma unroll
    for (int d = 1; d < 64; d <<= 1) dp += __shfl_xor(dp, d, 64);
    if (l == 0) zpd[wv] = dp;
  }
  __syncthreads();
  if (tid < 8) {
    double v = zpd[tid];
#pragma unroll
    for (int d = 1; d < 8; d <<= 1) v += __shfl_xor(v, d, 64);
    if (tid == 0) {
      const float z = (float)(v + (double)fcb);
      f32x2 zv = (f32x2){z, 128.0f};
      stg_cohx2(ztag + 160 + (bid << 1), zv);   // parity (127&1)=1
    }
  }
  if (bid != 0) return;
  if (tid < 40) {
    const f32x4 zv = poll1(ztag + 160 + (tid << 2), 128.0f);
    z_lds[2 * tid]     = zv.x;
    z_lds[2 * tid + 1] = zv.z;
  }
  __syncthreads();
  if (wv == 0) {
    float dxa, dxb;
    do_sample(127, l, z_lds, gum, uni, true, dout, dxa, dxb);
  }
}

extern "C" void kernel_launch(void* const* d_in, const int* in_sizes, int n_in,
                              void* d_out, int out_size, void* d_ws, size_t ws_size,
                              hipStream_t stream) {
  (void)in_sizes; (void)n_in; (void)out_size;
  const size_t need = (8192 + 320) * sizeof(float);
  if (ws_size < need) return;
  const float* W_ih = (const float*)d_in[0];
  const float* W_hh = (const float*)d_in[1];
  const float* b_ih = (const float*)d_in[2];
  const float* b_hh = (const float*)d_in[3];
  const float* fc1w = (const float*)d_in[4];
  const float* fc1b = (const float*)d_in[5];
  const float* fc2w = (const float*)d_in[6];
  const float* fc2b = (const float*)d_in[7];
  (void)hipMemsetAsync(d_ws, 0, need, stream);
  hipLaunchKernelGGL(ctrl_kernel, dim3(NBLK), dim3(TPB), 0, stream,
                     W_ih, W_hh, b_ih, b_hh, fc1w, fc1b, fc2w, fc2b,
                     (float*)d_out, d_ws);
}

// Round 12
// 978.186 us; speedup vs baseline: 1.1099x; 1.1099x over previous
//
#include <hip/hip_runtime.h>
#include <stdint.h>

#define NBLK 256
#define TPB  512

typedef float f32x4 __attribute__((ext_vector_type(4)));
typedef float f32x2 __attribute__((ext_vector_type(2)));

// ---------------- threefry2x32 (exact JAX partitionable semantics) -------
__device__ __forceinline__ uint32_t rotl32(uint32_t x, int r) {
  return (x << r) | (x >> (32 - r));
}

__device__ __forceinline__ void tf2x32(uint32_t k0, uint32_t k1,
                                       uint32_t x0, uint32_t x1,
                                       uint32_t& o0, uint32_t& o1) {
  const uint32_t k2 = k0 ^ k1 ^ 0x1BD11BDAu;
#define TFR(r) x0 += x1; x1 = rotl32(x1, (r)); x1 ^= x0;
  x0 += k0; x1 += k1;
  TFR(13) TFR(15) TFR(26) TFR(6)
  x0 += k1; x1 += k2 + 1u;
  TFR(17) TFR(29) TFR(16) TFR(24)
  x0 += k2; x1 += k0 + 2u;
  TFR(13) TFR(15) TFR(26) TFR(6)
  x0 += k0; x1 += k1 + 3u;
  TFR(17) TFR(29) TFR(16) TFR(24)
  x0 += k1; x1 += k2 + 4u;
  TFR(13) TFR(15) TFR(26) TFR(6)
  x0 += k2; x1 += k0 + 5u;
#undef TFR
  o0 = x0; o1 = x1;
}

__device__ __forceinline__ float bits_to_u01(uint32_t b) {
  return __uint_as_float((b >> 9) | 0x3f800000u) - 1.0f;
}

__device__ __forceinline__ float gumbel_from_bits(uint32_t b) {
  float u = bits_to_u01(b);
  u = (u == 0.0f) ? 1.17549435e-38f : u;
  return -logf(-logf(u));
}

__device__ __forceinline__ float sigf(float x) { return 1.0f / (1.0f + expf(-x)); }

// coherent (cross-XCD) accesses: sc0 sc1 -> device coherence point.
__device__ __forceinline__ f32x4 ldg_cohx4(const float* p) {
  f32x4 v;
  asm volatile("global_load_dwordx4 %0, %1, off sc0 sc1\n\ts_waitcnt vmcnt(0)"
               : "=v"(v) : "v"(p) : "memory");
  return v;
}
__device__ __forceinline__ void stg_cohx4(float* p, f32x4 v) {
  asm volatile("global_store_dwordx4 %0, %1, off sc0 sc1"
               :: "v"(p), "v"(v) : "memory");
}
__device__ __forceinline__ void stg_cohx2(float* p, f32x2 v) {
  asm volatile("global_store_dwordx2 %0, %1, off sc0 sc1"
               :: "v"(p), "v"(v) : "memory");
}
// dual coherent load (both in flight, one waitcnt) — R10 proven
__device__ __forceinline__ void ldg_coh2x4(const float* p1, const float* p2,
                                           f32x4& a, f32x4& b) {
  asm volatile("global_load_dwordx4 %0, %2, off sc0 sc1\n\t"
               "global_load_dwordx4 %1, %3, off sc0 sc1\n\t"
               "s_waitcnt vmcnt(0)"
               : "=&v"(a), "=&v"(b) : "v"(p1), "v"(p2) : "memory");
}

// ---------------- sampling for step s (redundant in every wave) ----------
__device__ __forceinline__ void do_sample(
    int s, int l, const float* __restrict__ zl,
    const float (*gum)[16], const float (*uni)[64],
    bool wr, float* __restrict__ dout,
    float& x_l, float& x2_l) {
  const int j = l & 7;
  float bv; int bi;
  {
    const float a_lo = gum[s][j]     + 2.5f * tanhf(zl[j] / 5.0f);
    const float a_hi = gum[s][j + 8] + 2.5f * tanhf(zl[j + 8] / 5.0f);
    if (a_hi > a_lo) { bv = a_hi; bi = j + 8; } else { bv = a_lo; bi = j; }
  }
#pragma unroll
  for (int d = 1; d < 8; d <<= 1) {
    const float ov = __shfl_xor(bv, d, 64);
    const int   oi = __shfl_xor(bi, d, 64);
    if (ov > bv || (ov == bv && oi < bi)) { bv = ov; bi = oi; }
  }
  const int idx1 = bi;

  const int j32 = l & 31;
  const int ci = s >> 1;
  const float cc = (float)ci;
  const float sa = -log1pf(cc * expf(-zl[16 + j32]));
  const float sb = -log1pf(cc * expf(-zl[48 + j32]));
  const float pa = expf(sa);
  const float pb = expf(sb);
  const float blo = ((uni[s][j32] < pa) && (j32 < ci)) ? 1.0f : 0.0f;
  const float bhi = ((uni[s][j32 + 32] < pb) && (j32 + 32 < ci)) ? 1.0f : 0.0f;

  const float v1 = __shfl(blo, (l - 16) & 63, 64);
  const float v2 = __shfl(bhi, (l - 48) & 63, 64);
  const float v3 = __shfl(bhi, (l + 16) & 63, 64);
  x_l  = (l < 16) ? ((idx1 == l) ? 1.0f : 0.0f) : ((l < 48) ? v1 : v2);
  x2_l = (l < 16) ? v3 : 0.0f;

  if (wr) {
    const float lgt = 2.5f * tanhf(zl[l & 15] / 5.0f);
    float mx = lgt;
#pragma unroll
    for (int d = 1; d < 16; d <<= 1) mx = fmaxf(mx, __shfl_xor(mx, d, 64));
    float sm = expf(lgt - mx);
#pragma unroll
    for (int d = 1; d < 16; d <<= 1) sm += __shfl_xor(sm, d, 64);
    const float ls = lgt - mx - logf(sm);
    if (l < 16) {
      dout[s * 16 + l] = ls;
      dout[10240 + s * 16 + l] = (idx1 == l) ? 1.0f : 0.0f;
    }
    if (l < 32) {
      dout[2048 + s * 64 + l]       = sa;
      dout[2048 + s * 64 + 32 + l]  = sb;
      dout[12288 + s * 64 + l]      = blo;
      dout[12288 + s * 64 + 32 + l] = bhi;
    }
  }
}

__device__ __forceinline__ int perm(int e) {
  return (((e >> 2) & 7) << 8) | ((e >> 5) << 2) | (e & 3);
}

// ---------------- persistent controller kernel ----------------
// 256 blocks x 512 threads, 1 block/CU (launch_bounds(512,1) -> 2 waves/
// SIMD -> 256-reg budget; R10 confirmed no spill at this geometry).
// Poll loops throttled with s_sleep(2) on miss: cuts the LLC poll-traffic
// that inflates publish->visibility latency (R11: 2x traffic => +9% dur).
__global__ void __launch_bounds__(TPB, 1)
ctrl_kernel(const float* __restrict__ W_ih, const float* __restrict__ W_hh,
            const float* __restrict__ b_ih, const float* __restrict__ b_hh,
            const float* __restrict__ fc1w, const float* __restrict__ fc1b,
            const float* __restrict__ fc2w, const float* __restrict__ fc2b,
            float* __restrict__ dout, void* __restrict__ ws) {
  const int bid = blockIdx.x;
  const int tid = threadIdx.x;
  const int wv = tid >> 6;    // wave 0..7
  const int l  = tid & 63;

  // ws: htag[2][4096] dwords (2048 elems x (v,t)) ; ztag[2][160] dwords
  float* htag = (float*)ws;
  float* ztag = htag + 8192;

  __shared__ float gum[128][16];
  __shared__ float uni[128][64];
  __shared__ __align__(16) float h_lds[2048];
  __shared__ float z_lds[80];
  __shared__ float gbuf[8][4];
  __shared__ double zpd[8];
  __shared__ float c_lds[8];

  // --- RNG tables (partitionable threefry; verified R3) ---
  if (tid < 8) c_lds[tid] = 0.0f;
  {
    const int s = tid >> 2;   // step
    const int c = tid & 3;    // chunk
    uint32_t ka, kb, c0, c1, d0, d1;
    tf2x32(0u, 42u, 0u, (uint32_t)s, ka, kb);
    tf2x32(ka, kb, 0u, 0u, c0, c1);
    tf2x32(ka, kb, 0u, 1u, d0, d1);
#pragma unroll
    for (int q = 0; q < 4; ++q) {
      const int j = 4 * c + q;
      uint32_t lo, hi;
      tf2x32(c0, c1, 0u, (uint32_t)j, lo, hi);
      gum[s][j] = gumbel_from_bits(lo ^ hi);
    }
#pragma unroll
    for (int q = 0; q < 16; ++q) {
      const int j = 16 * c + q;
      uint32_t lo, hi;
      tf2x32(d0, d1, 0u, (uint32_t)j, lo, hi);
      uni[s][j] = bits_to_u01(lo ^ hi);
    }
  }

  // --- register-resident W_hh slice: 4 rows x 32 cols per lane ---
  const int g   = wv >> 1;          // gate 0..3
  const int kb4 = (wv & 1) << 2;    // elem base 0 or 4
  f32x4 Wr[4][8];
  float wih_a[4], wih_b[4], bsum[4];
#pragma unroll
  for (int rr = 0; rr < 4; ++rr) {
    const int r = g * 2048 + bid * 8 + kb4 + rr;
    const float* wp = W_hh + (size_t)r * 2048 + 32 * l;
#pragma unroll
    for (int m = 0; m < 8; ++m)
      Wr[rr][m] = *reinterpret_cast<const f32x4*>(wp + 4 * m);
    wih_a[rr] = W_ih[r * 80 + l];
    wih_b[rr] = (l < 16) ? W_ih[r * 80 + 64 + l] : 0.0f;
    bsum[rr] = b_ih[r] + b_hh[r];
  }
  // PIN: with the 256-reg budget these stay resident (R10: no spill)
#pragma unroll
  for (int rr = 0; rr < 4; ++rr) {
#pragma unroll
    for (int m = 0; m < 8; ++m)
      asm volatile("" : "+v"(Wr[rr][m]));
  }

  f32x2 fcA = (f32x2){0.f, 0.f}, fcB = (f32x2){0.f, 0.f};
  float fcb = 0.0f;
  if (bid < 80) {
    const float* fp = (bid < 16) ? (fc1w + (size_t)bid * 2048)
                                 : (fc2w + (size_t)(bid - 16) * 2048);
    fcA = *reinterpret_cast<const f32x2*>(fp + 2 * tid);          // cols 2t,2t+1
    fcB = *reinterpret_cast<const f32x2*>(fp + 1024 + 2 * tid);   // +1024
    fcb = (bid < 16) ? fc1b[bid] : fc2b[bid - 16];
  }
  __syncthreads();

  float x_l = 0.0f, x2_l = 0.0f;
  const int p0 = perm(2 * tid), p1 = perm(2 * tid + 1);
  const int p2 = perm(1024 + 2 * tid), p3 = perm(1024 + 2 * tid + 1);

#pragma unroll 1
  for (int i = 0; i < 128; ++i) {
    // A: acquire h_i (two 16B (v,t,v,t) chunks per thread); stage to LDS.
    f32x4 hv1 = (f32x4){0.f, 0.f, 0.f, 0.f};
    f32x4 hv2 = (f32x4){0.f, 0.f, 0.f, 0.f};
    if (i > 0) {
      const float tagf = (float)i;
      const float* s1 = htag + ((i & 1) << 12) + (tid << 2);
      const float* s2 = s1 + 2048;
      for (;;) {
        ldg_coh2x4(s1, s2, hv1, hv2);
        if (hv1.y == tagf && hv1.w == tagf && hv2.y == tagf && hv2.w == tagf)
          break;
        __builtin_amdgcn_s_sleep(2);
      }
    }
    h_lds[p0] = hv1.x;
    h_lds[p1] = hv1.z;
    h_lds[p2] = hv2.x;
    h_lds[p3] = hv2.z;

    // B: heads start z_{i-1} = fc_row . relu(h_i) from the polled regs.
    if (i > 0 && bid < 80) {
      double dp = fma((double)fcA.x, (double)fmaxf(hv1.x, 0.0f),
                      (double)fcA.y * (double)fmaxf(hv1.z, 0.0f));
      dp = fma((double)fcB.x, (double)fmaxf(hv2.x, 0.0f), dp);
      dp = fma((double)fcB.y, (double)fmaxf(hv2.z, 0.0f), dp);
#pragma unroll
      for (int d = 1; d < 64; d <<= 1) dp += __shfl_xor(dp, d, 64);
      if (l == 0) zpd[wv] = dp;
    }
    __syncthreads();  // h_lds + zpd visible
    if (i > 0 && bid < 80 && tid < 8) {
      double v = zpd[tid];
#pragma unroll
      for (int d = 1; d < 8; d <<= 1) v += __shfl_xor(v, d, 64);
      if (tid == 0) {
        const float z = (float)(v + (double)fcb);
        f32x2 zv = (f32x2){z, (float)i};   // tag = i
        stg_cohx2(ztag + (((i - 1) & 1) * 160) + (bid << 1), zv);
      }
    }

    // C: W_hh @ h_i partial from registers (overlaps the z round-trip)
    float acc[4] = {0.f, 0.f, 0.f, 0.f};
#pragma unroll
    for (int m = 0; m < 8; ++m) {
      const f32x4 H = *reinterpret_cast<const f32x4*>(h_lds + (m << 8) + (l << 2));
#pragma unroll
      for (int rr = 0; rr < 4; ++rr) {
        acc[rr] = fmaf(Wr[rr][m].x, H.x, acc[rr]);
        acc[rr] = fmaf(Wr[rr][m].y, H.y, acc[rr]);
        acc[rr] = fmaf(Wr[rr][m].z, H.z, acc[rr]);
        acc[rr] = fmaf(Wr[rr][m].w, H.w, acc[rr]);
      }
    }

    // D: poll z_{i-1}, stage, sample x_i
    if (i > 0) {
      const int s = i - 1;
      if (tid < 40) {
        const float tagzf = (float)i;
        const float* src = ztag + ((s & 1) * 160) + (tid << 2);
        f32x4 zv;
        for (;;) {
          zv = ldg_cohx4(src);
          if (zv.y == tagzf && zv.w == tagzf) break;
          __builtin_amdgcn_s_sleep(2);
        }
        z_lds[2 * tid]     = zv.x;
        z_lds[2 * tid + 1] = zv.z;
      }
      __syncthreads();
      do_sample(s, l, z_lds, gum, uni, (bid == 0 && wv == 0), dout, x_l, x2_l);
    }

    // E: fold W_ih@x, butterfly-reduce, LSTM cell, publish h_{i+1}
#pragma unroll
    for (int rr = 0; rr < 4; ++rr)
      acc[rr] = fmaf(wih_a[rr], x_l, fmaf(wih_b[rr], x2_l, acc[rr]));
#pragma unroll
    for (int rr = 0; rr < 4; ++rr) {
#pragma unroll
      for (int d = 1; d < 64; d <<= 1)
        acc[rr] += __shfl_xor(acc[rr], d, 64);
    }
    if (l == 0) {
#pragma unroll
      for (int rr = 0; rr < 4; ++rr)
        gbuf[wv][rr] = acc[rr] + bsum[rr];
    }
    __syncthreads();
    if (tid < 8) {
      const int t = tid;
      const float gI = gbuf[0 + (t >> 2)][t & 3];
      const float gF = gbuf[2 + (t >> 2)][t & 3];
      const float gG = gbuf[4 + (t >> 2)][t & 3];
      const float gO = gbuf[6 + (t >> 2)][t & 3];
      const float cn = sigf(gF) * c_lds[t] + sigf(gI) * tanhf(gG);
      const float hn = sigf(gO) * tanhf(cn);
      c_lds[t] = cn;
      const float hnn = __shfl(hn, t + 1, 64);
      if ((t & 1) == 0) {
        const float tagf = (float)(i + 1);
        f32x4 out4 = (f32x4){hn, tagf, hnn, tagf};
        stg_cohx4(htag + (((i + 1) & 1) << 12) + (((bid << 3) + t) << 1), out4);
      }
    }
  }

  // ---- epilogue: z_127 (from h_128) and outputs for step 127 ----
  if (bid >= 80) return;
  {
    const float tagf = 128.0f;
    const float* s1 = htag + (tid << 2);   // buffer 0 holds h_128
    const float* s2 = s1 + 2048;
    f32x4 hv1, hv2;
    for (;;) {
      ldg_coh2x4(s1, s2, hv1, hv2);
      if (hv1.y == tagf && hv1.w == tagf && hv2.y == tagf && hv2.w == tagf)
        break;
      __builtin_amdgcn_s_sleep(2);
    }
    double dp = fma((double)fcA.x, (double)fmaxf(hv1.x, 0.0f),
                    (double)fcA.y * (double)fmaxf(hv1.z, 0.0f));
    dp = fma((double)fcB.x, (double)fmaxf(hv2.x, 0.0f), dp);
    dp = fma((double)fcB.y, (double)fmaxf(hv2.z, 0.0f), dp);
#pragma unroll
    for (int d = 1; d < 64; d <<= 1) dp += __shfl_xor(dp, d, 64);
    if (l == 0) zpd[wv] = dp;
  }
  __syncthreads();
  if (tid < 8) {
    double v = zpd[tid];
#pragma unroll
    for (int d = 1; d < 8; d <<= 1) v += __shfl_xor(v, d, 64);
    if (tid == 0) {
      const float z = (float)(v + (double)fcb);
      f32x2 zv = (f32x2){z, 128.0f};
      stg_cohx2(ztag + 160 + (bid << 1), zv);   // parity (127&1)=1
    }
  }
  if (bid != 0) return;
  if (tid < 40) {
    const float tagzf = 128.0f;
    const float* src = ztag + 160 + (tid << 2);
    f32x4 zv;
    for (;;) {
      zv = ldg_cohx4(src);
      if (zv.y == tagzf && zv.w == tagzf) break;
      __builtin_amdgcn_s_sleep(2);
    }
    z_lds[2 * tid]     = zv.x;
    z_lds[2 * tid + 1] = zv.z;
  }
  __syncthreads();
  if (wv == 0) {
    float dxa, dxb;
    do_sample(127, l, z_lds, gum, uni, true, dout, dxa, dxb);
  }
}

extern "C" void kernel_launch(void* const* d_in, const int* in_sizes, int n_in,
                              void* d_out, int out_size, void* d_ws, size_t ws_size,
                              hipStream_t stream) {
  (void)in_sizes; (void)n_in; (void)out_size;
  const size_t need = (8192 + 320) * sizeof(float);
  if (ws_size < need) return;
  const float* W_ih = (const float*)d_in[0];
  const float* W_hh = (const float*)d_in[1];
  const float* b_ih = (const float*)d_in[2];
  const float* b_hh = (const float*)d_in[3];
  const float* fc1w = (const float*)d_in[4];
  const float* fc1b = (const float*)d_in[5];
  const float* fc2w = (const float*)d_in[6];
  const float* fc2b = (const float*)d_in[7];
  (void)hipMemsetAsync(d_ws, 0, need, stream);
  hipLaunchKernelGGL(ctrl_kernel, dim3(NBLK), dim3(TPB), 0, stream,
                     W_ih, W_hh, b_ih, b_hh, fc1w, fc1b, fc2w, fc2b,
                     (float*)d_out, d_ws);
}

// Round 13
// 816.837 us; speedup vs baseline: 1.3292x; 1.1975x over previous
//
#include <hip/hip_runtime.h>
#include <stdint.h>

#define NBLK 256
#define TPB  512
#define HREP 8192   // dwords per h replica: [2][4096]
#define ZREP 320    // dwords per z replica: [2][160]

typedef float f32x4 __attribute__((ext_vector_type(4)));
typedef float f32x2 __attribute__((ext_vector_type(2)));

// ---------------- threefry2x32 (exact JAX partitionable semantics) -------
__device__ __forceinline__ uint32_t rotl32(uint32_t x, int r) {
  return (x << r) | (x >> (32 - r));
}

__device__ __forceinline__ void tf2x32(uint32_t k0, uint32_t k1,
                                       uint32_t x0, uint32_t x1,
                                       uint32_t& o0, uint32_t& o1) {
  const uint32_t k2 = k0 ^ k1 ^ 0x1BD11BDAu;
#define TFR(r) x0 += x1; x1 = rotl32(x1, (r)); x1 ^= x0;
  x0 += k0; x1 += k1;
  TFR(13) TFR(15) TFR(26) TFR(6)
  x0 += k1; x1 += k2 + 1u;
  TFR(17) TFR(29) TFR(16) TFR(24)
  x0 += k2; x1 += k0 + 2u;
  TFR(13) TFR(15) TFR(26) TFR(6)
  x0 += k0; x1 += k1 + 3u;
  TFR(17) TFR(29) TFR(16) TFR(24)
  x0 += k1; x1 += k2 + 4u;
  TFR(13) TFR(15) TFR(26) TFR(6)
  x0 += k2; x1 += k0 + 5u;
#undef TFR
  o0 = x0; o1 = x1;
}

__device__ __forceinline__ float bits_to_u01(uint32_t b) {
  return __uint_as_float((b >> 9) | 0x3f800000u) - 1.0f;
}

__device__ __forceinline__ float gumbel_from_bits(uint32_t b) {
  float u = bits_to_u01(b);
  u = (u == 0.0f) ? 1.17549435e-38f : u;
  return -logf(-logf(u));
}

__device__ __forceinline__ float sigf(float x) { return 1.0f / (1.0f + expf(-x)); }

// coherent (cross-XCD) accesses: sc0 sc1 -> device coherence point.
__device__ __forceinline__ f32x4 ldg_cohx4(const float* p) {
  f32x4 v;
  asm volatile("global_load_dwordx4 %0, %1, off sc0 sc1\n\ts_waitcnt vmcnt(0)"
               : "=v"(v) : "v"(p) : "memory");
  return v;
}
__device__ __forceinline__ void stg_cohx4(float* p, f32x4 v) {
  asm volatile("global_store_dwordx4 %0, %1, off sc0 sc1"
               :: "v"(p), "v"(v) : "memory");
}
__device__ __forceinline__ void stg_cohx2(float* p, f32x2 v) {
  asm volatile("global_store_dwordx2 %0, %1, off sc0 sc1"
               :: "v"(p), "v"(v) : "memory");
}
// dual coherent load (both in flight, one waitcnt) — R10 proven
__device__ __forceinline__ void ldg_coh2x4(const float* p1, const float* p2,
                                           f32x4& a, f32x4& b) {
  asm volatile("global_load_dwordx4 %0, %2, off sc0 sc1\n\t"
               "global_load_dwordx4 %1, %3, off sc0 sc1\n\t"
               "s_waitcnt vmcnt(0)"
               : "=&v"(a), "=&v"(b) : "v"(p1), "v"(p2) : "memory");
}

// ---------------- sampling for step s (redundant in every wave) ----------
__device__ __forceinline__ void do_sample(
    int s, int l, const float* __restrict__ zl,
    const float (*gum)[16], const float (*uni)[64],
    bool wr, float* __restrict__ dout,
    float& x_l, float& x2_l) {
  const int j = l & 7;
  float bv; int bi;
  {
    const float a_lo = gum[s][j]     + 2.5f * tanhf(zl[j] / 5.0f);
    const float a_hi = gum[s][j + 8] + 2.5f * tanhf(zl[j + 8] / 5.0f);
    if (a_hi > a_lo) { bv = a_hi; bi = j + 8; } else { bv = a_lo; bi = j; }
  }
#pragma unroll
  for (int d = 1; d < 8; d <<= 1) {
    const float ov = __shfl_xor(bv, d, 64);
    const int   oi = __shfl_xor(bi, d, 64);
    if (ov > bv || (ov == bv && oi < bi)) { bv = ov; bi = oi; }
  }
  const int idx1 = bi;

  const int j32 = l & 31;
  const int ci = s >> 1;
  const float cc = (float)ci;
  const float sa = -log1pf(cc * expf(-zl[16 + j32]));
  const float sb = -log1pf(cc * expf(-zl[48 + j32]));
  const float pa = expf(sa);
  const float pb = expf(sb);
  const float blo = ((uni[s][j32] < pa) && (j32 < ci)) ? 1.0f : 0.0f;
  const float bhi = ((uni[s][j32 + 32] < pb) && (j32 + 32 < ci)) ? 1.0f : 0.0f;

  const float v1 = __shfl(blo, (l - 16) & 63, 64);
  const float v2 = __shfl(bhi, (l - 48) & 63, 64);
  const float v3 = __shfl(bhi, (l + 16) & 63, 64);
  x_l  = (l < 16) ? ((idx1 == l) ? 1.0f : 0.0f) : ((l < 48) ? v1 : v2);
  x2_l = (l < 16) ? v3 : 0.0f;

  if (wr) {
    const float lgt = 2.5f * tanhf(zl[l & 15] / 5.0f);
    float mx = lgt;
#pragma unroll
    for (int d = 1; d < 16; d <<= 1) mx = fmaxf(mx, __shfl_xor(mx, d, 64));
    float sm = expf(lgt - mx);
#pragma unroll
    for (int d = 1; d < 16; d <<= 1) sm += __shfl_xor(sm, d, 64);
    const float ls = lgt - mx - logf(sm);
    if (l < 16) {
      dout[s * 16 + l] = ls;
      dout[10240 + s * 16 + l] = (idx1 == l) ? 1.0f : 0.0f;
    }
    if (l < 32) {
      dout[2048 + s * 64 + l]       = sa;
      dout[2048 + s * 64 + 32 + l]  = sb;
      dout[12288 + s * 64 + l]      = blo;
      dout[12288 + s * 64 + 32 + l] = bhi;
    }
  }
}

__device__ __forceinline__ int perm(int e) {
  return (((e >> 2) & 7) << 8) | ((e >> 5) << 2) | (e & 3);
}

// ---------------- persistent controller kernel ----------------
// 256 blocks x 512 threads, 1 block/CU. Exchange buffers are REPLICATED
// R-fold: consumers poll replica bid%R, producers write all R copies.
// Cuts pollers-per-LLC-line ~Rx (R12 analysis: same-line queueing at the
// coherence point is the dominant per-step residue).
__global__ void __launch_bounds__(TPB, 1)
ctrl_kernel(const float* __restrict__ W_ih, const float* __restrict__ W_hh,
            const float* __restrict__ b_ih, const float* __restrict__ b_hh,
            const float* __restrict__ fc1w, const float* __restrict__ fc1b,
            const float* __restrict__ fc2w, const float* __restrict__ fc2b,
            float* __restrict__ dout, void* __restrict__ ws, int R) {
  const int bid = blockIdx.x;
  const int tid = threadIdx.x;
  const int wv = tid >> 6;    // wave 0..7
  const int l  = tid & 63;

  float* htag = (float*)ws;               // [R][2][4096] dwords
  float* ztag = htag + (size_t)R * HREP;  // [R][2][160] dwords
  float* hmy  = htag + (size_t)(bid % R) * HREP;
  float* zmy  = ztag + (size_t)(bid % R) * ZREP;

  __shared__ float gum[128][16];
  __shared__ float uni[128][64];
  __shared__ __align__(16) float h_lds[2048];
  __shared__ float z_lds[80];
  __shared__ float gbuf[8][4];
  __shared__ double zpd[8];
  __shared__ float c_lds[8];

  // --- RNG tables (partitionable threefry; verified R3) ---
  if (tid < 8) c_lds[tid] = 0.0f;
  {
    const int s = tid >> 2;   // step
    const int c = tid & 3;    // chunk
    uint32_t ka, kb, c0, c1, d0, d1;
    tf2x32(0u, 42u, 0u, (uint32_t)s, ka, kb);
    tf2x32(ka, kb, 0u, 0u, c0, c1);
    tf2x32(ka, kb, 0u, 1u, d0, d1);
#pragma unroll
    for (int q = 0; q < 4; ++q) {
      const int j = 4 * c + q;
      uint32_t lo, hi;
      tf2x32(c0, c1, 0u, (uint32_t)j, lo, hi);
      gum[s][j] = gumbel_from_bits(lo ^ hi);
    }
#pragma unroll
    for (int q = 0; q < 16; ++q) {
      const int j = 16 * c + q;
      uint32_t lo, hi;
      tf2x32(d0, d1, 0u, (uint32_t)j, lo, hi);
      uni[s][j] = bits_to_u01(lo ^ hi);
    }
  }

  // --- register-resident W_hh slice: 4 rows x 32 cols per lane ---
  const int g   = wv >> 1;          // gate 0..3
  const int kb4 = (wv & 1) << 2;    // elem base 0 or 4
  f32x4 Wr[4][8];
  float wih_a[4], wih_b[4], bsum[4];
#pragma unroll
  for (int rr = 0; rr < 4; ++rr) {
    const int r = g * 2048 + bid * 8 + kb4 + rr;
    const float* wp = W_hh + (size_t)r * 2048 + 32 * l;
#pragma unroll
    for (int m = 0; m < 8; ++m)
      Wr[rr][m] = *reinterpret_cast<const f32x4*>(wp + 4 * m);
    wih_a[rr] = W_ih[r * 80 + l];
    wih_b[rr] = (l < 16) ? W_ih[r * 80 + 64 + l] : 0.0f;
    bsum[rr] = b_ih[r] + b_hh[r];
  }
  // PIN: with the 256-reg budget these stay resident (R10: no spill)
#pragma unroll
  for (int rr = 0; rr < 4; ++rr) {
#pragma unroll
    for (int m = 0; m < 8; ++m)
      asm volatile("" : "+v"(Wr[rr][m]));
  }

  f32x2 fcA = (f32x2){0.f, 0.f}, fcB = (f32x2){0.f, 0.f};
  float fcb = 0.0f;
  if (bid < 80) {
    const float* fp = (bid < 16) ? (fc1w + (size_t)bid * 2048)
                                 : (fc2w + (size_t)(bid - 16) * 2048);
    fcA = *reinterpret_cast<const f32x2*>(fp + 2 * tid);          // cols 2t,2t+1
    fcB = *reinterpret_cast<const f32x2*>(fp + 1024 + 2 * tid);   // +1024
    fcb = (bid < 16) ? fc1b[bid] : fc2b[bid - 16];
  }
  __syncthreads();

  float x_l = 0.0f, x2_l = 0.0f;
  const int p0 = perm(2 * tid), p1 = perm(2 * tid + 1);
  const int p2 = perm(1024 + 2 * tid), p3 = perm(1024 + 2 * tid + 1);

#pragma unroll 1
  for (int i = 0; i < 128; ++i) {
    // A: acquire h_i from own replica; stage to LDS.
    f32x4 hv1 = (f32x4){0.f, 0.f, 0.f, 0.f};
    f32x4 hv2 = (f32x4){0.f, 0.f, 0.f, 0.f};
    if (i > 0) {
      const float tagf = (float)i;
      const float* s1 = hmy + ((i & 1) << 12) + (tid << 2);
      const float* s2 = s1 + 2048;
      for (;;) {
        ldg_coh2x4(s1, s2, hv1, hv2);
        if (hv1.y == tagf && hv1.w == tagf && hv2.y == tagf && hv2.w == tagf)
          break;
        __builtin_amdgcn_s_sleep(2);
      }
    }
    h_lds[p0] = hv1.x;
    h_lds[p1] = hv1.z;
    h_lds[p2] = hv2.x;
    h_lds[p3] = hv2.z;

    // B: heads start z_{i-1} = fc_row . relu(h_i) from the polled regs.
    if (i > 0 && bid < 80) {
      double dp = fma((double)fcA.x, (double)fmaxf(hv1.x, 0.0f),
                      (double)fcA.y * (double)fmaxf(hv1.z, 0.0f));
      dp = fma((double)fcB.x, (double)fmaxf(hv2.x, 0.0f), dp);
      dp = fma((double)fcB.y, (double)fmaxf(hv2.z, 0.0f), dp);
#pragma unroll
      for (int d = 1; d < 64; d <<= 1) dp += __shfl_xor(dp, d, 64);
      if (l == 0) zpd[wv] = dp;
    }
    __syncthreads();  // h_lds + zpd visible
    if (i > 0 && bid < 80 && tid < 8) {
      double v = zpd[tid];
#pragma unroll
      for (int d = 1; d < 8; d <<= 1) v += __shfl_xor(v, d, 64);
      if (tid == 0) {
        const float z = (float)(v + (double)fcb);
        f32x2 zv = (f32x2){z, (float)i};   // tag = i
        for (int r = 0; r < R; ++r)
          stg_cohx2(ztag + (size_t)r * ZREP + (((i - 1) & 1) * 160) + (bid << 1), zv);
      }
    }

    // C: W_hh @ h_i partial from registers (overlaps the z round-trip)
    float acc[4] = {0.f, 0.f, 0.f, 0.f};
#pragma unroll
    for (int m = 0; m < 8; ++m) {
      const f32x4 H = *reinterpret_cast<const f32x4*>(h_lds + (m << 8) + (l << 2));
#pragma unroll
      for (int rr = 0; rr < 4; ++rr) {
        acc[rr] = fmaf(Wr[rr][m].x, H.x, acc[rr]);
        acc[rr] = fmaf(Wr[rr][m].y, H.y, acc[rr]);
        acc[rr] = fmaf(Wr[rr][m].z, H.z, acc[rr]);
        acc[rr] = fmaf(Wr[rr][m].w, H.w, acc[rr]);
      }
    }

    // D: poll z_{i-1} from own replica, stage, sample x_i
    if (i > 0) {
      const int s = i - 1;
      if (tid < 40) {
        const float tagzf = (float)i;
        const float* src = zmy + ((s & 1) * 160) + (tid << 2);
        f32x4 zv;
        for (;;) {
          zv = ldg_cohx4(src);
          if (zv.y == tagzf && zv.w == tagzf) break;
          __builtin_amdgcn_s_sleep(2);
        }
        z_lds[2 * tid]     = zv.x;
        z_lds[2 * tid + 1] = zv.z;
      }
      __syncthreads();
      do_sample(s, l, z_lds, gum, uni, (bid == 0 && wv == 0), dout, x_l, x2_l);
    }

    // E: fold W_ih@x, butterfly-reduce, LSTM cell, publish h_{i+1}
#pragma unroll
    for (int rr = 0; rr < 4; ++rr)
      acc[rr] = fmaf(wih_a[rr], x_l, fmaf(wih_b[rr], x2_l, acc[rr]));
#pragma unroll
    for (int rr = 0; rr < 4; ++rr) {
#pragma unroll
      for (int d = 1; d < 64; d <<= 1)
        acc[rr] += __shfl_xor(acc[rr], d, 64);
    }
    if (l == 0) {
#pragma unroll
      for (int rr = 0; rr < 4; ++rr)
        gbuf[wv][rr] = acc[rr] + bsum[rr];
    }
    __syncthreads();
    if (tid < 8) {
      const int t = tid;
      const float gI = gbuf[0 + (t >> 2)][t & 3];
      const float gF = gbuf[2 + (t >> 2)][t & 3];
      const float gG = gbuf[4 + (t >> 2)][t & 3];
      const float gO = gbuf[6 + (t >> 2)][t & 3];
      const float cn = sigf(gF) * c_lds[t] + sigf(gI) * tanhf(gG);
      const float hn = sigf(gO) * tanhf(cn);
      c_lds[t] = cn;
      const float hnn = __shfl(hn, t + 1, 64);
      if ((t & 1) == 0) {
        const float tagf = (float)(i + 1);
        f32x4 out4 = (f32x4){hn, tagf, hnn, tagf};
        const int off = (((i + 1) & 1) << 12) + (((bid << 3) + t) << 1);
        for (int r = 0; r < R; ++r)
          stg_cohx4(htag + (size_t)r * HREP + off, out4);
      }
    }
  }

  // ---- epilogue: z_127 (from h_128) and outputs for step 127 ----
  if (bid >= 80) return;
  {
    const float tagf = 128.0f;
    const float* s1 = hmy + (tid << 2);   // buffer 0 holds h_128
    const float* s2 = s1 + 2048;
    f32x4 hv1, hv2;
    for (;;) {
      ldg_coh2x4(s1, s2, hv1, hv2);
      if (hv1.y == tagf && hv1.w == tagf && hv2.y == tagf && hv2.w == tagf)
        break;
      __builtin_amdgcn_s_sleep(2);
    }
    double dp = fma((double)fcA.x, (double)fmaxf(hv1.x, 0.0f),
                    (double)fcA.y * (double)fmaxf(hv1.z, 0.0f));
    dp = fma((double)fcB.x, (double)fmaxf(hv2.x, 0.0f), dp);
    dp = fma((double)fcB.y, (double)fmaxf(hv2.z, 0.0f), dp);
#pragma unroll
    for (int d = 1; d < 64; d <<= 1) dp += __shfl_xor(dp, d, 64);
    if (l == 0) zpd[wv] = dp;
  }
  __syncthreads();
  if (tid < 8) {
    double v = zpd[tid];
#pragma unroll
    for (int d = 1; d < 8; d <<= 1) v += __shfl_xor(v, d, 64);
    if (tid == 0) {
      const float z = (float)(v + (double)fcb);
      f32x2 zv = (f32x2){z, 128.0f};
      for (int r = 0; r < R; ++r)
        stg_cohx2(ztag + (size_t)r * ZREP + 160 + (bid << 1), zv);  // parity 1
    }
  }
  if (bid != 0) return;
  if (tid < 40) {
    const float tagzf = 128.0f;
    const float* src = zmy + 160 + (tid << 2);
    f32x4 zv;
    for (;;) {
      zv = ldg_cohx4(src);
      if (zv.y == tagzf && zv.w == tagzf) break;
      __builtin_amdgcn_s_sleep(2);
    }
    z_lds[2 * tid]     = zv.x;
    z_lds[2 * tid + 1] = zv.z;
  }
  __syncthreads();
  if (wv == 0) {
    float dxa, dxb;
    do_sample(127, l, z_lds, gum, uni, true, dout, dxa, dxb);
  }
}

extern "C" void kernel_launch(void* const* d_in, const int* in_sizes, int n_in,
                              void* d_out, int out_size, void* d_ws, size_t ws_size,
                              hipStream_t stream) {
  (void)in_sizes; (void)n_in; (void)out_size;
  int R = 8;
  while (R > 1 && (size_t)R * (HREP + ZREP) * sizeof(float) > ws_size) R >>= 1;
  const size_t need = (size_t)R * (HREP + ZREP) * sizeof(float);
  if (ws_size < need) return;
  const float* W_ih = (const float*)d_in[0];
  const float* W_hh = (const float*)d_in[1];
  const float* b_ih = (const float*)d_in[2];
  const float* b_hh = (const float*)d_in[3];
  const float* fc1w = (const float*)d_in[4];
  const float* fc1b = (const float*)d_in[5];
  const float* fc2w = (const float*)d_in[6];
  const float* fc2b = (const float*)d_in[7];
  (void)hipMemsetAsync(d_ws, 0, need, stream);
  hipLaunchKernelGGL(ctrl_kernel, dim3(NBLK), dim3(TPB), 0, stream,
                     W_ih, W_hh, b_ih, b_hh, fc1w, fc1b, fc2w, fc2b,
                     (float*)d_out, d_ws, R);
}